// Round 2
// baseline (47.313 us; speedup 1.0000x reference)
//
#include <hip/hip_runtime.h>

// EarthMoversDistanceLoss: out[b] = sum_j (cumsum(x-y, axis=1)[b,j])^2
// N=131072 rows, BINS=256.
//
// One 64-lane wave per row; lane l holds float4 of bins [4l,4l+3].
// Software-pipelined grid-stride loop: next row's x/y loads are issued
// BEFORE the current row's dependent shfl scan chain, doubling memory-level
// parallelism per wave (the scan is ~12 dependent cross-lane ops during
// which the wave would otherwise issue no loads).

constexpr int BINS = 256;

__device__ __forceinline__ float process_row(float4 xv, float4 yv, int lane)
{
    const float d0 = xv.x - yv.x;
    const float d1 = xv.y - yv.y;
    const float d2 = xv.z - yv.z;
    const float d3 = xv.w - yv.w;

    // per-lane inclusive prefix over the 4 local diffs
    const float p0 = d0;
    const float p1 = p0 + d1;
    const float p2 = p1 + d2;
    const float p3 = p2 + d3;

    // 64-lane inclusive scan of lane totals
    float t = p3;
    #pragma unroll
    for (int off = 1; off < 64; off <<= 1) {
        float v = __shfl_up(t, off, 64);
        t += (lane >= off) ? v : 0.0f;
    }
    const float offset = t - p3;  // exclusive prefix

    const float c0 = offset + p0;
    const float c1 = offset + p1;
    const float c2 = offset + p2;
    const float c3 = offset + p3;

    float sq = c0 * c0 + c1 * c1 + c2 * c2 + c3 * c3;

    // wave-wide sum reduction
    #pragma unroll
    for (int off = 32; off >= 1; off >>= 1)
        sq += __shfl_xor(sq, off, 64);

    return sq;
}

__global__ __launch_bounds__(256) void emd_loss_kernel(
    const float* __restrict__ x,
    const float* __restrict__ y,
    float* __restrict__ out,
    int n_rows)
{
    const int lane = threadIdx.x & 63;
    const int waves_per_block = blockDim.x >> 6;
    int row = blockIdx.x * waves_per_block + (threadIdx.x >> 6);
    const int row_stride = gridDim.x * waves_per_block;

    if (row >= n_rows) return;

    const float4* __restrict__ xp = reinterpret_cast<const float4*>(x);
    const float4* __restrict__ yp = reinterpret_cast<const float4*>(y);

    float4 xv = xp[(size_t)row * (BINS / 4) + lane];
    float4 yv = yp[(size_t)row * (BINS / 4) + lane];

    for (;;) {
        const int next = row + row_stride;
        const bool have_next = next < n_rows;
        float4 nx, ny;
        if (have_next) {
            // issue next row's loads before the dependent scan chain
            nx = xp[(size_t)next * (BINS / 4) + lane];
            ny = yp[(size_t)next * (BINS / 4) + lane];
        }

        const float sq = process_row(xv, yv, lane);
        if (lane == 0) out[row] = sq;

        if (!have_next) break;
        xv = nx;
        yv = ny;
        row = next;
    }
}

extern "C" void kernel_launch(void* const* d_in, const int* in_sizes, int n_in,
                              void* d_out, int out_size, void* d_ws, size_t ws_size,
                              hipStream_t stream)
{
    const float* x = (const float*)d_in[0];
    const float* y = (const float*)d_in[1];
    float* out = (float*)d_out;
    const int n_rows = in_sizes[0] / BINS;  // 131072

    // 2048 blocks x 256 threads = 8192 waves = 32 waves/CU, grid-stride.
    const int block = 256;
    const int waves_per_block = block / 64;
    int grid = 2048;
    const int total_wave_groups = (n_rows + waves_per_block - 1) / waves_per_block;
    if (grid > total_wave_groups) grid = total_wave_groups;

    emd_loss_kernel<<<grid, block, 0, stream>>>(x, y, out, n_rows);
}

// Round 3
// 42.177 us; speedup vs baseline: 1.1218x; 1.1218x over previous
//
#include <hip/hip_runtime.h>

// EarthMoversDistanceLoss: out[b] = sum_j (cumsum(x-y, axis=1)[b,j])^2
// N=131072 rows, BINS=256.
//
// Regime (round-1/2 counters): streaming-BW-bound. 268.4 MB reads + 0.5 MB
// writes at ~6.0 TB/s effective (≈95% of the 6.3 TB/s achievable ceiling;
// ~half the reads are L3 hits across replays, FETCH_SIZE ≈ 134 MB).
// Prefetch pipelining regressed (R2: 47.3 vs 44.9 µs) -> not latency-bound.
//
// This version: exact-cover grid, one 64-lane wave per row, no loop.
// Lane l holds float4 of bins [4l,4l+3]; per-lane prefix -> 64-lane shfl_up
// scan -> square-sum -> shfl_xor reduce -> lane 0 stores.

constexpr int BINS = 256;

__global__ __launch_bounds__(256) void emd_loss_kernel(
    const float* __restrict__ x,
    const float* __restrict__ y,
    float* __restrict__ out,
    int n_rows)
{
    const int lane = threadIdx.x & 63;
    const int row = blockIdx.x * (blockDim.x >> 6) + (threadIdx.x >> 6);
    if (row >= n_rows) return;

    const float4 xv = reinterpret_cast<const float4*>(x)[(size_t)row * (BINS / 4) + lane];
    const float4 yv = reinterpret_cast<const float4*>(y)[(size_t)row * (BINS / 4) + lane];

    const float d0 = xv.x - yv.x;
    const float d1 = xv.y - yv.y;
    const float d2 = xv.z - yv.z;
    const float d3 = xv.w - yv.w;

    // per-lane inclusive prefix over the 4 local diffs
    const float p0 = d0;
    const float p1 = p0 + d1;
    const float p2 = p1 + d2;
    const float p3 = p2 + d3;

    // 64-lane inclusive scan of lane totals
    float t = p3;
    #pragma unroll
    for (int off = 1; off < 64; off <<= 1) {
        float v = __shfl_up(t, off, 64);
        t += (lane >= off) ? v : 0.0f;
    }
    const float offset = t - p3;  // exclusive prefix of lane totals

    const float c0 = offset + p0;
    const float c1 = offset + p1;
    const float c2 = offset + p2;
    const float c3 = offset + p3;

    float sq = c0 * c0 + c1 * c1 + c2 * c2 + c3 * c3;

    // wave-wide sum reduction
    #pragma unroll
    for (int off = 32; off >= 1; off >>= 1)
        sq += __shfl_xor(sq, off, 64);

    if (lane == 0) out[row] = sq;
}

extern "C" void kernel_launch(void* const* d_in, const int* in_sizes, int n_in,
                              void* d_out, int out_size, void* d_ws, size_t ws_size,
                              hipStream_t stream)
{
    const float* x = (const float*)d_in[0];
    const float* y = (const float*)d_in[1];
    float* out = (float*)d_out;
    const int n_rows = in_sizes[0] / BINS;  // 131072

    // Exact cover: 4 rows (waves) per 256-thread block, no grid-stride loop.
    const int block = 256;
    const int rows_per_block = block / 64;
    const int grid = (n_rows + rows_per_block - 1) / rows_per_block;  // 32768

    emd_loss_kernel<<<grid, block, 0, stream>>>(x, y, out, n_rows);
}